// Round 10
// baseline (100.484 us; speedup 1.0000x reference)
//
#include <hip/hip_runtime.h>
#include <hip/hip_bf16.h>

#define N 8192
#define D 512
#define BM 128
#define BN 128
#define BK 64
#define NCB (N / BN)   // 64 column blocks
#define NKT (D / BK)   // 8 K tiles
#define NTRI (NCB * (NCB + 1) / 2)  // 2080 upper-triangle blocks (2080 % 8 == 0)
#define INVT 14.285714285714286f

typedef __attribute__((ext_vector_type(8))) short bf16x8;
typedef __attribute__((ext_vector_type(4))) float f32x4;
typedef __attribute__((ext_vector_type(8))) unsigned short u16x8;

__device__ __forceinline__ unsigned short f2bf(float f) {
  __hip_bfloat16 h = __float2bfloat16(f);
  return *reinterpret_cast<unsigned short*>(&h);
}

// ---------------- kernel 1: L2-normalize rows -> bf16; zero out[0] ----------
__global__ __launch_bounds__(256) void k_normalize(const float* __restrict__ x,
                                                   unsigned short* __restrict__ fb,
                                                   float* __restrict__ out) {
  const int row = blockIdx.x * 4 + (threadIdx.x >> 6);
  const int lane = threadIdx.x & 63;
  const float* rp = x + (size_t)row * D + lane * 8;
  float4 v0 = *reinterpret_cast<const float4*>(rp);
  float4 v1 = *reinterpret_cast<const float4*>(rp + 4);
  float s = v0.x*v0.x + v0.y*v0.y + v0.z*v0.z + v0.w*v0.w
          + v1.x*v1.x + v1.y*v1.y + v1.z*v1.z + v1.w*v1.w;
  #pragma unroll
  for (int m = 1; m < 64; m <<= 1) s += __shfl_xor(s, m);
  float inv = 1.0f / fmaxf(sqrtf(s), 1e-12f);
  u16x8 o;
  o[0] = f2bf(v0.x*inv); o[1] = f2bf(v0.y*inv); o[2] = f2bf(v0.z*inv); o[3] = f2bf(v0.w*inv);
  o[4] = f2bf(v1.x*inv); o[5] = f2bf(v1.y*inv); o[6] = f2bf(v1.z*inv); o[7] = f2bf(v1.w*inv);
  *reinterpret_cast<u16x8*>(fb + (size_t)row * D + lane * 8) = o;
  if (blockIdx.x == 0 && threadIdx.x == 0) out[0] = 0.0f;
}

// ---------------- kernel 2: fused GEMM + exp/mask/count reductions ----------
// R7-validated bf16 body (57us, 0 conflicts, no spills, XCD-chunked triangle
// swizzle) + R9's epilogue: also accumulates the exact positive-pair COUNT
// (replaces the histogram kernel) and uses an LDS overlay on As for the
// cross-wave reduction.  // R9 post-mortem: i8 path regressed; bf16 K-loop
// kept verbatim, only dispatch structure from R9 retained.
#define GLOAD_LDS16(g, l) __builtin_amdgcn_global_load_lds( \
    (const __attribute__((address_space(1))) unsigned int*)(g), \
    (__attribute__((address_space(3))) unsigned int*)(l), 16, 0, 0)

__global__ __launch_bounds__(256, 3) void k_gemm(
    const unsigned short* __restrict__ fb, const int* __restrict__ labels,
    float* __restrict__ part_e, float* __restrict__ part_p,
    float* __restrict__ part_c) {
  __shared__ __align__(16) short As[BM * BK];   // 16 KB (epilogue overlay: 1536 floats)
  __shared__ __align__(16) short Bs[BN * BK];   // 16 KB
  __shared__ int labR[BM];
  __shared__ int labC[BN];

  const int tid = threadIdx.x;
  const int lane = tid & 63;
  const int w = tid >> 6;
  const int wr = w >> 1, wc = w & 1;
  const int l15 = lane & 15;

  // XCD-chunked bijective swizzle (NTRI % 8 == 0)
  const int b0 = blockIdx.x;
  const int t = (b0 & 7) * (NTRI / 8) + (b0 >> 3);

  // triangle index -> (bx, by), by <= bx
  int bx = (int)((sqrtf(8.0f * (float)t + 1.0f) - 1.0f) * 0.5f);
  while ((bx + 1) * (bx + 2) / 2 <= t) ++bx;
  while (bx * (bx + 1) / 2 > t) --bx;
  const int by = t - bx * (bx + 1) / 2;
  const bool offdiag = (bx != by);

  const int rowA0 = by * BM, rowB0 = bx * BN;

  if (tid < BM) labR[tid] = labels[rowA0 + tid];
  else          labC[tid - BM] = labels[rowB0 + (tid - BM)];

  f32x4 acc[4][4] = {};
  const int sslot = tid & 7;

  for (int kt = 0; kt < NKT; ++kt) {
    if (kt) __syncthreads();
    const int kbase = kt * BK;
    #pragma unroll
    for (int it = 0; it < 4; ++it) {
      int r = (it * 256 + tid) >> 3;
      int kcol = ((sslot ^ (r & 7)) << 3) + kbase;
      GLOAD_LDS16(fb + (size_t)(rowA0 + r) * D + kcol,
                  (char*)As + it * 4096 + w * 1024);
    }
    #pragma unroll
    for (int it = 0; it < 4; ++it) {
      int r = (it * 256 + tid) >> 3;
      int kcol = ((sslot ^ (r & 7)) << 3) + kbase;
      GLOAD_LDS16(fb + (size_t)(rowB0 + r) * D + kcol,
                  (char*)Bs + it * 4096 + w * 1024);
    }
    __syncthreads();

    #pragma unroll
    for (int kk = 0; kk < BK; kk += 32) {
      bf16x8 af[4], bg[4];
      #pragma unroll
      for (int m = 0; m < 4; ++m) {
        int ar = wr * 64 + m * 16 + l15;
        int kb = (kk + ((lane >> 4) << 3)) * 2;
        af[m] = *reinterpret_cast<const bf16x8*>(
            (const char*)As + ar * 128 + (kb ^ ((ar & 7) << 4)));
      }
      #pragma unroll
      for (int n = 0; n < 4; ++n) {
        int br = wc * 64 + n * 16 + l15;
        int kb = (kk + ((lane >> 4) << 3)) * 2;
        bg[n] = *reinterpret_cast<const bf16x8*>(
            (const char*)Bs + br * 128 + (kb ^ ((br & 7) << 4)));
      }
      #pragma unroll
      for (int m = 0; m < 4; ++m)
        #pragma unroll
        for (int n = 0; n < 4; ++n)
          acc[m][n] = __builtin_amdgcn_mfma_f32_16x16x32_bf16(af[m], bg[n], acc[m][n], 0, 0, 0);
    }
  }

  // ---- fused epilogue: exp-sum, masked-sum, masked-count ----
  __syncthreads();                     // all waves done with As/Bs ds_reads
  float* fo = (float*)As;              // overlay: 1536 floats in 16 KB
  // [0]e_row[2][128] [256]p_row [512]c_row [768]e_col[2][128] [1024]p_col [1280]c_col

  float ecol[4] = {}, pcol[4] = {}, ccol[4] = {};
  int lc[4];
  #pragma unroll
  for (int n = 0; n < 4; ++n)
    lc[n] = labC[wc * 64 + n * 16 + l15];

  #pragma unroll
  for (int m = 0; m < 4; ++m)
    #pragma unroll
    for (int r = 0; r < 4; ++r) {
      int rowl = wr * 64 + m * 16 + ((lane >> 4) << 2) + r;
      int lrv = labR[rowl];
      float e = 0.0f, p = 0.0f, cn = 0.0f;
      #pragma unroll
      for (int n = 0; n < 4; ++n) {
        float s = acc[m][n][r] * INVT;
        float ex = __expf(s);
        bool match = (lrv == lc[n]);
        e += ex;
        p += match ? s : 0.0f;
        cn += match ? 1.0f : 0.0f;
        ecol[n] += ex;
        pcol[n] += match ? s : 0.0f;
        ccol[n] += match ? 1.0f : 0.0f;
      }
      #pragma unroll
      for (int msk = 1; msk < 16; msk <<= 1) {
        e += __shfl_xor(e, msk);
        p += __shfl_xor(p, msk);
        cn += __shfl_xor(cn, msk);
      }
      if (l15 == 0) {
        fo[wc * 128 + rowl] = e;
        fo[256 + wc * 128 + rowl] = p;
        fo[512 + wc * 128 + rowl] = cn;
      }
    }

  if (offdiag) {
    #pragma unroll
    for (int n = 0; n < 4; ++n) {
      float e = ecol[n], p = pcol[n], cn = ccol[n];
      e += __shfl_xor(e, 16); e += __shfl_xor(e, 32);
      p += __shfl_xor(p, 16); p += __shfl_xor(p, 32);
      cn += __shfl_xor(cn, 16); cn += __shfl_xor(cn, 32);
      if (lane < 16) {
        int cidx = wc * 64 + n * 16 + l15;
        fo[768 + wr * 128 + cidx] = e;
        fo[1024 + wr * 128 + cidx] = p;
        fo[1280 + wr * 128 + cidx] = cn;
      }
    }
  }
  __syncthreads();

  if (tid < BM) {
    float e = fo[tid] + fo[128 + tid];
    float p = fo[256 + tid] + fo[384 + tid];
    float cn = fo[512 + tid] + fo[640 + tid];
    size_t off = (size_t)bx * N + rowA0 + tid;
    part_e[off] = e; part_p[off] = p; part_c[off] = cn;
  } else if (offdiag) {
    int cidx = tid - BM;
    float e = fo[768 + cidx] + fo[896 + cidx];
    float p = fo[1024 + cidx] + fo[1152 + cidx];
    float cn = fo[1280 + cidx] + fo[1408 + cidx];
    size_t off = (size_t)by * N + rowB0 + cidx;
    part_e[off] = e; part_p[off] = p; part_c[off] = cn;
  }
}

// ---------------- kernel 3: per-row loss + atomic mean ----------------------
__global__ __launch_bounds__(256) void k_final(
    const float* __restrict__ part_e, const float* __restrict__ part_p,
    const float* __restrict__ part_c, float* __restrict__ out) {
  const int i = blockIdx.x * 256 + threadIdx.x;
  float e = 0.0f, p = 0.0f, c = 0.0f;
  #pragma unroll 8
  for (int cb = 0; cb < NCB; ++cb) {
    e += part_e[(size_t)cb * N + i];
    p += part_p[(size_t)cb * N + i];
    c += part_c[(size_t)cb * N + i];
  }
  float li = logf(e) - p / c;
  #pragma unroll
  for (int m = 1; m < 64; m <<= 1) li += __shfl_xor(li, m);
  __shared__ float red[4];
  if ((threadIdx.x & 63) == 0) red[threadIdx.x >> 6] = li;
  __syncthreads();
  if (threadIdx.x == 0)
    atomicAdd(out, (red[0] + red[1] + red[2] + red[3]) * (1.0f / (float)N));
}

extern "C" void kernel_launch(void* const* d_in, const int* in_sizes, int n_in,
                              void* d_out, int out_size, void* d_ws, size_t ws_size,
                              hipStream_t stream) {
  const float* x = (const float*)d_in[0];
  const int* labels = (const int*)d_in[1];
  float* out = (float*)d_out;
  char* ws = (char*)d_ws;

  unsigned short* fb = (unsigned short*)ws;                      // 8 MB bf16 normalized
  float* part_e = (float*)(ws + (size_t)8  * 1024 * 1024);       // 2 MB (64 x 8192)
  float* part_p = (float*)(ws + (size_t)10 * 1024 * 1024);       // 2 MB
  float* part_c = (float*)(ws + (size_t)12 * 1024 * 1024);       // 2 MB

  k_normalize<<<N / 4, 256, 0, stream>>>(x, fb, out);
  k_gemm<<<NTRI, 256, 0, stream>>>(fb, labels, part_e, part_p, part_c);
  k_final<<<N / 256, 256, 0, stream>>>(part_e, part_p, part_c, out);
}

// Round 11
// 83.341 us; speedup vs baseline: 1.2057x; 1.2057x over previous
//
#include <hip/hip_runtime.h>
#include <hip/hip_bf16.h>

#define N 8192
#define D 512
#define BM 128
#define BN 128
#define BK 64
#define NCB (N / BN)   // 64 column blocks
#define NKT (D / BK)   // 8 K tiles
#define NTRI (NCB * (NCB + 1) / 2)  // 2080 upper-triangle blocks (2080 % 8 == 0)
#define INVT 14.285714285714286f

typedef __attribute__((ext_vector_type(8))) short bf16x8;
typedef __attribute__((ext_vector_type(4))) float f32x4;
typedef __attribute__((ext_vector_type(8))) unsigned short u16x8;

__device__ __forceinline__ unsigned short f2bf(float f) {
  __hip_bfloat16 h = __float2bfloat16(f);
  return *reinterpret_cast<unsigned short*>(&h);
}

// ---------------- kernel 1: L2-normalize rows -> bf16; zero out[0] ----------
__global__ __launch_bounds__(256) void k_normalize(const float* __restrict__ x,
                                                   unsigned short* __restrict__ fb,
                                                   float* __restrict__ out) {
  const int row = blockIdx.x * 4 + (threadIdx.x >> 6);
  const int lane = threadIdx.x & 63;
  const float* rp = x + (size_t)row * D + lane * 8;
  float4 v0 = *reinterpret_cast<const float4*>(rp);
  float4 v1 = *reinterpret_cast<const float4*>(rp + 4);
  float s = v0.x*v0.x + v0.y*v0.y + v0.z*v0.z + v0.w*v0.w
          + v1.x*v1.x + v1.y*v1.y + v1.z*v1.z + v1.w*v1.w;
  #pragma unroll
  for (int m = 1; m < 64; m <<= 1) s += __shfl_xor(s, m);
  float inv = 1.0f / fmaxf(sqrtf(s), 1e-12f);
  u16x8 o;
  o[0] = f2bf(v0.x*inv); o[1] = f2bf(v0.y*inv); o[2] = f2bf(v0.z*inv); o[3] = f2bf(v0.w*inv);
  o[4] = f2bf(v1.x*inv); o[5] = f2bf(v1.y*inv); o[6] = f2bf(v1.z*inv); o[7] = f2bf(v1.w*inv);
  *reinterpret_cast<u16x8*>(fb + (size_t)row * D + lane * 8) = o;
  if (blockIdx.x == 0 && threadIdx.x == 0) out[0] = 0.0f;
}

// ---------------- kernel 2: fused GEMM + exp-rowsum + masked-sum -------------
// R7 kernel VERBATIM (measured: 57us, VGPR 80, WRITE 4MB, 0 conflicts).
// R10 post-mortem: adding a third (count) accumulator to this epilogue spilled
// ~36 regs/thread (83MB scratch writes) — epilogue register budget is
// razor-thin at (256,3); do NOT add state here. Count lives in k_final's hist.
#define GLOAD_LDS16(g, l) __builtin_amdgcn_global_load_lds( \
    (const __attribute__((address_space(1))) unsigned int*)(g), \
    (__attribute__((address_space(3))) unsigned int*)(l), 16, 0, 0)

__global__ __launch_bounds__(256, 3) void k_gemm(
    const unsigned short* __restrict__ fb, const int* __restrict__ labels,
    float* __restrict__ part_e, float* __restrict__ part_p) {
  __shared__ __align__(16) short As[BM * BK];
  __shared__ __align__(16) short Bs[BN * BK];
  __shared__ float e_part[2][BM];   // row-partials, indexed by wc
  __shared__ float p_part[2][BM];
  __shared__ float e_cpart[2][BN];  // col-partials, indexed by wr
  __shared__ float p_cpart[2][BN];
  __shared__ int labR[BM];
  __shared__ int labC[BN];

  const int tid = threadIdx.x;
  const int lane = tid & 63;
  const int w = tid >> 6;
  const int wr = w >> 1, wc = w & 1;

  // XCD-chunked bijective swizzle (NTRI % 8 == 0)
  const int b0 = blockIdx.x;
  const int t = (b0 & 7) * (NTRI / 8) + (b0 >> 3);

  // triangle index -> (bx, by), by <= bx
  int bx = (int)((sqrtf(8.0f * (float)t + 1.0f) - 1.0f) * 0.5f);
  while ((bx + 1) * (bx + 2) / 2 <= t) ++bx;
  while (bx * (bx + 1) / 2 > t) --bx;
  const int by = t - bx * (bx + 1) / 2;
  const bool offdiag = (bx != by);

  const int rowA0 = by * BM, rowB0 = bx * BN;

  if (tid < BM) labR[tid] = labels[rowA0 + tid];
  else          labC[tid - BM] = labels[rowB0 + (tid - BM)];

  f32x4 acc[4][4] = {};
  const int sslot = tid & 7;

  for (int kt = 0; kt < NKT; ++kt) {
    if (kt) __syncthreads();
    const int kbase = kt * BK;
    #pragma unroll
    for (int it = 0; it < 4; ++it) {
      int r = (it * 256 + tid) >> 3;
      int kcol = ((sslot ^ (r & 7)) << 3) + kbase;
      GLOAD_LDS16(fb + (size_t)(rowA0 + r) * D + kcol,
                  (char*)As + it * 4096 + w * 1024);
    }
    #pragma unroll
    for (int it = 0; it < 4; ++it) {
      int r = (it * 256 + tid) >> 3;
      int kcol = ((sslot ^ (r & 7)) << 3) + kbase;
      GLOAD_LDS16(fb + (size_t)(rowB0 + r) * D + kcol,
                  (char*)Bs + it * 4096 + w * 1024);
    }
    __syncthreads();

    #pragma unroll
    for (int kk = 0; kk < BK; kk += 32) {
      bf16x8 af[4], bg[4];
      #pragma unroll
      for (int m = 0; m < 4; ++m) {
        int ar = wr * 64 + m * 16 + (lane & 15);
        int kb = (kk + ((lane >> 4) << 3)) * 2;
        af[m] = *reinterpret_cast<const bf16x8*>(
            (const char*)As + ar * 128 + (kb ^ ((ar & 7) << 4)));
      }
      #pragma unroll
      for (int n = 0; n < 4; ++n) {
        int br = wc * 64 + n * 16 + (lane & 15);
        int kb = (kk + ((lane >> 4) << 3)) * 2;
        bg[n] = *reinterpret_cast<const bf16x8*>(
            (const char*)Bs + br * 128 + (kb ^ ((br & 7) << 4)));
      }
      #pragma unroll
      for (int m = 0; m < 4; ++m)
        #pragma unroll
        for (int n = 0; n < 4; ++n)
          acc[m][n] = __builtin_amdgcn_mfma_f32_16x16x32_bf16(af[m], bg[n], acc[m][n], 0, 0, 0);
    }
  }

  // ---- fused epilogue (low register pressure: scalar e/p per (m,r)) ----
  float ecol[4] = {};
  float pcol[4] = {};
  int lc[4];
  #pragma unroll
  for (int n = 0; n < 4; ++n)
    lc[n] = labC[wc * 64 + n * 16 + (lane & 15)];

  #pragma unroll
  for (int m = 0; m < 4; ++m)
    #pragma unroll
    for (int r = 0; r < 4; ++r) {
      int lrv = labR[wr * 64 + m * 16 + ((lane >> 4) << 2) + r];
      float e = 0.0f, p = 0.0f;
      #pragma unroll
      for (int n = 0; n < 4; ++n) {
        float s = acc[m][n][r] * INVT;
        float ex = __expf(s);
        float pm = (lrv == lc[n]) ? s : 0.0f;
        e += ex; p += pm;
        ecol[n] += ex; pcol[n] += pm;
      }
      #pragma unroll
      for (int msk = 1; msk < 16; msk <<= 1) {
        e += __shfl_xor(e, msk);
        p += __shfl_xor(p, msk);
      }
      if ((lane & 15) == 0) {
        int row = wr * 64 + m * 16 + ((lane >> 4) << 2) + r;
        e_part[wc][row] = e;
        p_part[wc][row] = p;
      }
    }

  // col-partials: reduce across the 4 row-groups (lane>>4)
  if (offdiag) {
    #pragma unroll
    for (int n = 0; n < 4; ++n) {
      float e = ecol[n], p = pcol[n];
      e += __shfl_xor(e, 16); e += __shfl_xor(e, 32);
      p += __shfl_xor(p, 16); p += __shfl_xor(p, 32);
      if ((lane >> 4) == 0) {
        int c = wc * 64 + n * 16 + (lane & 15);
        e_cpart[wr][c] = e;
        p_cpart[wr][c] = p;
      }
    }
  }
  __syncthreads();

  if (tid < BM) {
    float e = e_part[0][tid] + e_part[1][tid];
    float p = p_part[0][tid] + p_part[1][tid];
    size_t off = (size_t)bx * N + rowA0 + tid;
    part_e[off] = e;
    part_p[off] = p;
  } else if (offdiag) {
    int c = tid - BM;
    float e = e_cpart[0][c] + e_cpart[1][c];
    float p = p_cpart[0][c] + p_cpart[1][c];
    size_t off = (size_t)by * N + rowB0 + c;
    part_e[off] = e;
    part_p[off] = p;
  }
}

// ---------------- kernel 3: per-row loss + atomic mean ----------------------
// Per-block LDS label histogram (R7-validated) + atomicAdd finalize (R9).
__global__ __launch_bounds__(256) void k_final(
    const float* __restrict__ part_e, const float* __restrict__ part_p,
    const int* __restrict__ labels, float* __restrict__ out) {
  __shared__ int h[128];
  const int tid = threadIdx.x;
  if (tid < 128) h[tid] = 0;
  __syncthreads();
  for (int j = tid; j < N; j += 256) atomicAdd(&h[labels[j]], 1);

  const int i = blockIdx.x * 256 + tid;
  float e = 0.0f, p = 0.0f;
  #pragma unroll 8
  for (int cb = 0; cb < NCB; ++cb) {
    e += part_e[(size_t)cb * N + i];
    p += part_p[(size_t)cb * N + i];
  }
  __syncthreads();
  float cnt = (float)h[labels[i]];
  float li = logf(e) - p / cnt;
  #pragma unroll
  for (int m = 1; m < 64; m <<= 1) li += __shfl_xor(li, m);
  __shared__ float red[4];
  if ((tid & 63) == 0) red[tid >> 6] = li;
  __syncthreads();
  if (tid == 0)
    atomicAdd(out, (red[0] + red[1] + red[2] + red[3]) * (1.0f / (float)N));
}

extern "C" void kernel_launch(void* const* d_in, const int* in_sizes, int n_in,
                              void* d_out, int out_size, void* d_ws, size_t ws_size,
                              hipStream_t stream) {
  const float* x = (const float*)d_in[0];
  const int* labels = (const int*)d_in[1];
  float* out = (float*)d_out;
  char* ws = (char*)d_ws;

  unsigned short* fb = (unsigned short*)ws;                      // 8 MB bf16 normalized
  float* part_e = (float*)(ws + (size_t)8  * 1024 * 1024);       // 2 MB (64 x 8192)
  float* part_p = (float*)(ws + (size_t)10 * 1024 * 1024);       // 2 MB

  k_normalize<<<N / 4, 256, 0, stream>>>(x, fb, out);
  k_gemm<<<NTRI, 256, 0, stream>>>(fb, labels, part_e, part_p);
  k_final<<<N / 256, 256, 0, stream>>>(part_e, part_p, labels, out);
}